// Round 5
// baseline (92.106 us; speedup 1.0000x reference)
//
#include <hip/hip_runtime.h>

// Locally-connected 2d: x[32,16,66,66], weight[1,32,16,64,64,9], bias[1,32,64,64]
// out[32,32,64,64] fp32.
//
// R5: R4 structure, but CSTG 8->4 (LDS 36->18 KB) + __launch_bounds__(256,8)
// -> 8 blocks/CU (32 waves/CU, 100% occupancy target) to hide L2/L3 load
// latency (R4 was latency-bound: VALUBusy 21.7%, HBM 9%, occupancy 38.8%).
// VGPR must stay <= 64 (R4 used 56).

#define B_   32
#define CO_  32
#define CI_  16
#define H_   64
#define W_   64
#define XH_  66
#define XW_  66
#define CSTG 4                 // c's per LDS stage
#define ROWS (2 * CSTG)        // 8 rows (2 o x 4 c)
#define ROWF (W_ * 9)          // 576 floats per row

__global__ __launch_bounds__(256, 8) void lc2d_kernel(
    const float* __restrict__ x,
    const float* __restrict__ wt,
    const float* __restrict__ bias,
    float* __restrict__ out) {
  __shared__ float wlds[ROWS * ROWF];  // 4608 floats = 18 KB

  // 1024 blocks, 8 XCDs -> bijective swizzle, contiguous 128-block chunks.
  const int d = blockIdx.x;
  const int L = (d & 7) * 128 + (d >> 3);
  const int opair = L & 15;        // innermost: x-sharing blocks adjacent
  const int h     = L >> 4;
  const int w   = threadIdx.x;     // 0..63 (lane = w)
  const int bg  = threadIdx.y;     // 0..3 batch group
  const int tid = bg * 64 + w;     // 0..255
  const int o0 = opair * 2;
  const int b0 = bg * 8;

  float acc[2][8];
#pragma unroll
  for (int i = 0; i < 2; ++i)
#pragma unroll
    for (int b = 0; b < 8; ++b) acc[i][b] = 0.0f;

  const size_t x_cstride = (size_t)XH_ * XW_;           // 4356
  const size_t x_bstride = (size_t)CI_ * x_cstride;     // 69696
  const float* xbase = x + (size_t)b0 * x_bstride + (size_t)h * XW_ + w;

  for (int s = 0; s < 4; ++s) {
    const int c0 = s * CSTG;
    __syncthreads();  // next stage must not overwrite rows still being read

    // Cooperative stage: 8 rows x 144 float4 = 1152 float4; 4-5 per thread.
    // Row r = o*CSTG+cc; each global row (2304 B) is 16-B aligned.
#pragma unroll
    for (int i = 0; i < 5; ++i) {
      const int f4 = tid + i * 256;        // 0..1279
      if (f4 < ROWS * 144) {
        const int r = f4 / 144;            // magic-mul
        const int within = f4 - r * 144;
        const int o = r >> 2, cc = r & 3;
        const float4* src = (const float4*)(
            wt + (((size_t)(o0 + o) * CI_ + (c0 + cc)) * H_ + h) * (size_t)(W_ * 9)) + within;
        *((float4*)&wlds[(size_t)r * ROWF] + within) = *src;
      }
    }
    __syncthreads();

    for (int cc = 0; cc < CSTG; ++cc) {
      const int c = c0 + cc;
      float w0[9], w1[9];
      const float* l0 = &wlds[(size_t)cc * ROWF + w * 9];
      const float* l1 = &wlds[(size_t)(CSTG + cc) * ROWF + w * 9];
#pragma unroll
      for (int k = 0; k < 9; ++k) {
        w0[k] = l0[k];
        w1[k] = l1[k];
      }

      const float* xc = xbase + (size_t)c * x_cstride;
#pragma unroll
      for (int b = 0; b < 8; ++b) {
        const float* xb = xc + (size_t)b * x_bstride;
        float xv[9];
#pragma unroll
        for (int i = 0; i < 3; ++i) {
#pragma unroll
          for (int j = 0; j < 3; ++j) xv[3 * i + j] = xb[i * XW_ + j];
        }
#pragma unroll
        for (int k = 0; k < 9; ++k) {
          acc[0][b] = fmaf(w0[k], xv[k], acc[0][b]);
          acc[1][b] = fmaf(w1[k], xv[k], acc[1][b]);
        }
      }
    }
  }

  const float bv0 = bias[((size_t)o0 * H_ + h) * W_ + w];
  const float bv1 = bias[((size_t)(o0 + 1) * H_ + h) * W_ + w];
  const size_t hw = (size_t)h * W_ + w;
#pragma unroll
  for (int b = 0; b < 8; ++b) {
    float* op = out + (((size_t)(b0 + b) * CO_ + o0) * H_ * W_) + hw;
    op[0]               = acc[0][b] + bv0;
    op[(size_t)H_ * W_] = acc[1][b] + bv1;
  }
}

extern "C" void kernel_launch(void* const* d_in, const int* in_sizes, int n_in,
                              void* d_out, int out_size, void* d_ws, size_t ws_size,
                              hipStream_t stream) {
  const float* x    = (const float*)d_in[0];
  const float* wt   = (const float*)d_in[1];
  const float* bias = (const float*)d_in[2];
  float* out = (float*)d_out;

  dim3 block(64, 4, 1);
  dim3 grid(1024, 1, 1);  // 16 opairs * 64 h
  lc2d_kernel<<<grid, block, 0, stream>>>(x, wt, bias, out);
}

// Round 6
// 72.929 us; speedup vs baseline: 1.2630x; 1.2630x over previous
//
#include <hip/hip_runtime.h>

// Locally-connected 2d: x[32,16,66,66], weight[1,32,16,64,64,9], bias[1,32,64,64]
// out[32,32,64,64] fp32.
//
// R6: attack VMEM instruction count (R4 issued 72 scalar x-loads/c-iter ~= 31us
// of pure VMEM issue). Thread = 2o x 4b x 2 adjacent w (lane = b2*32 + wg):
//  - x: two float2 loads per row cover both windows -> 24 VMEM/c-iter (8B, aligned).
//  - weights: LDS [o][cc][w][k] rows; per (o,k) read offsets {k, k+9} off one
//    base -> ds_read2_b32 (LDS pipe, separate from VMEM; 2-way alias = free).
// NO aggressive launch_bounds min-wave cap (R5 lesson: cap -> spill -> 120MB
// scratch writes). Cap 128 VGPR via (256,4).

#define B_   32
#define CO_  32
#define CI_  16
#define H_   64
#define W_   64
#define XH_  66
#define XW_  66
#define CSTG 4                 // c's per LDS stage
#define NROW (2 * CSTG)        // 8 rows (2 o x 4 c)
#define ROWF (W_ * 9)          // 576 floats per row

__global__ __launch_bounds__(256, 4) void lc2d_kernel(
    const float* __restrict__ x,
    const float* __restrict__ wt,
    const float* __restrict__ bias,
    float* __restrict__ out) {
  __shared__ float wlds[NROW * ROWF];  // 4608 floats = 18 KB

  // 1024 blocks, 8 XCDs -> bijective swizzle, contiguous 128-block chunks.
  const int d = blockIdx.x;
  const int L = (d & 7) * 128 + (d >> 3);
  const int opair = L & 15;        // innermost: x-sharing blocks adjacent
  const int h     = L >> 4;
  const int tx  = threadIdx.x;     // 0..63
  const int wg  = tx & 31;         // w-group: output cols 2wg, 2wg+1
  const int b2  = tx >> 5;         // 0/1 batch bit
  const int bg  = threadIdx.y;     // 0..3 batch group
  const int tid = bg * 64 + tx;    // 0..255
  const int o0  = opair * 2;

  float acc[2][4][2];              // [o][nb][jw]
#pragma unroll
  for (int o = 0; o < 2; ++o)
#pragma unroll
    for (int nb = 0; nb < 4; ++nb) {
      acc[o][nb][0] = 0.0f;
      acc[o][nb][1] = 0.0f;
    }

  const size_t x_cs = (size_t)XH_ * XW_;            // 4356
  const size_t x_bs = (size_t)CI_ * x_cs;           // 69696
  // base batch for nb=0 is bg*8 + b2; nb adds 2 each.
  const float* xbase = x + (size_t)(bg * 8 + b2) * x_bs + (size_t)h * XW_ + 2 * wg;

  for (int s = 0; s < 4; ++s) {
    __syncthreads();  // next stage must not overwrite rows still being read

    // Stage 8 rows x 144 float4 = 1152 float4 (whole-wave masked tail).
#pragma unroll
    for (int i = 0; i < 5; ++i) {
      const int f4 = tid + i * 256;
      if (f4 < NROW * 144) {
        const int r = f4 / 144;            // magic-mul
        const int within = f4 - r * 144;
        const int o = r >> 2, cc = r & 3;
        const float4* src = (const float4*)(
            wt + ((((size_t)(o0 + o) * CI_ + (s * CSTG + cc)) * H_ + h) * W_) * 9) + within;
        ((float4*)&wlds[(size_t)r * ROWF])[within] = *src;
      }
    }
    __syncthreads();

#pragma unroll
    for (int cc = 0; cc < CSTG; ++cc) {
      // Weight regs: wr[o][k][jw]; reads {k, k+9} dwords off one base -> ds_read2_b32.
      float wr[2][9][2];
#pragma unroll
      for (int o = 0; o < 2; ++o) {
        const float* wb = &wlds[(size_t)(o * CSTG + cc) * ROWF + wg * 18];
#pragma unroll
        for (int k = 0; k < 9; ++k) {
          wr[o][k][0] = wb[k];
          wr[o][k][1] = wb[9 + k];
        }
      }

      const float* xc = xbase + (size_t)(s * CSTG + cc) * x_cs;
#pragma unroll
      for (int nb = 0; nb < 4; ++nb) {
        const float* xb = xc + (size_t)(nb * 2) * x_bs;
#pragma unroll
        for (int i = 0; i < 3; ++i) {
          const float2 p = *(const float2*)(xb + i * XW_);
          const float2 q = *(const float2*)(xb + i * XW_ + 2);
          const float xv0 = p.x, xv1 = p.y, xv2 = q.x, xv3 = q.y;
#pragma unroll
          for (int o = 0; o < 2; ++o) {
            acc[o][nb][0] = fmaf(wr[o][3 * i + 0][0], xv0, acc[o][nb][0]);
            acc[o][nb][1] = fmaf(wr[o][3 * i + 0][1], xv1, acc[o][nb][1]);
            acc[o][nb][0] = fmaf(wr[o][3 * i + 1][0], xv1, acc[o][nb][0]);
            acc[o][nb][1] = fmaf(wr[o][3 * i + 1][1], xv2, acc[o][nb][1]);
            acc[o][nb][0] = fmaf(wr[o][3 * i + 2][0], xv2, acc[o][nb][0]);
            acc[o][nb][1] = fmaf(wr[o][3 * i + 2][1], xv3, acc[o][nb][1]);
          }
        }
      }
    }
  }

  // Epilogue: float2 stores (cols 2wg, 2wg+1 adjacent, 8B aligned).
  const float2 bv0 = *(const float2*)(bias + (size_t)o0 * H_ * W_ + h * W_ + 2 * wg);
  const float2 bv1 = *(const float2*)(bias + (size_t)(o0 + 1) * H_ * W_ + h * W_ + 2 * wg);
#pragma unroll
  for (int nb = 0; nb < 4; ++nb) {
    const int b = bg * 8 + nb * 2 + b2;
    float* op = out + ((size_t)b * CO_ + o0) * (H_ * W_) + h * W_ + 2 * wg;
    float2 r0, r1;
    r0.x = acc[0][nb][0] + bv0.x;
    r0.y = acc[0][nb][1] + bv0.y;
    r1.x = acc[1][nb][0] + bv1.x;
    r1.y = acc[1][nb][1] + bv1.y;
    *(float2*)op = r0;
    *(float2*)(op + (size_t)H_ * W_) = r1;
  }
}

extern "C" void kernel_launch(void* const* d_in, const int* in_sizes, int n_in,
                              void* d_out, int out_size, void* d_ws, size_t ws_size,
                              hipStream_t stream) {
  const float* x    = (const float*)d_in[0];
  const float* wt   = (const float*)d_in[1];
  const float* bias = (const float*)d_in[2];
  float* out = (float*)d_out;

  dim3 block(64, 4, 1);
  dim3 grid(1024, 1, 1);  // 16 opairs * 64 h
  lc2d_kernel<<<grid, block, 0, stream>>>(x, wt, bias, out);
}

// Round 7
// 56.660 us; speedup vs baseline: 1.6256x; 1.2871x over previous
//
#include <hip/hip_runtime.h>

// Locally-connected 2d via MFMA. Per (h,w): out[b,o] = sum_{c,k} X[b][ck] W[o][ck]
// = GEMM M=32(b), N=32(o), K=144 -> 16x v_mfma_f32_32x32x16_bf16 (K=16 per c,
// kappa 9..15 zero-padded via masked loads). One wave per (h,w).
// Weights: LDS-staged coalesced (R4 pattern), lanes gather B-fragments (b32,
// stride-36 dwords = 4-way bank alias). x: pre-transposed to xT[c][hh][ww][b]
// (b-minor) in d_ws so A-fragment loads (lane = b) are coalesced.
// fp32->bf16 cast: err ~0.01 absmax << 0.128 threshold; fp32 accumulate.

#define CI_ 16
#define H_  64
#define W_  64
#define XW_ 66

typedef float  f32x16 __attribute__((ext_vector_type(16)));
typedef short  s16x8  __attribute__((ext_vector_type(8)));

__device__ inline short f2bf(float f) {  // RNE float->bf16 (bit trick)
  unsigned u = __builtin_bit_cast(unsigned, f);
  u += 0x7fffu + ((u >> 16) & 1u);
  return (short)(u >> 16);
}

__global__ __launch_bounds__(256) void transpose_x(const float* __restrict__ x,
                                                   float* __restrict__ xT) {
  const int idx = blockIdx.x * 256 + threadIdx.x;  // 32*16*66*66 = 2230272 exact
  const int ww = idx % 66;
  int t = idx / 66;
  const int hh = t % 66; t /= 66;
  const int c = t % 16;
  const int b = t / 16;
  xT[(((size_t)c * 66 + hh) * 66 + ww) * 32 + b] = x[idx];
}

template <int TRANS>
__global__ __launch_bounds__(256, 4) void lc2d_mfma(
    const float* __restrict__ xs,   // xT (TRANS=1) or raw x (TRANS=0)
    const float* __restrict__ wt,
    const float* __restrict__ bias,
    float* __restrict__ out) {
  __shared__ float wlds[8 * 32 * 36];  // [cc][o][4w x 9k] = 36 KB

  // 1024 blocks; bijective XCD swizzle; h-contiguous chunks per XCD.
  const int d = blockIdx.x;
  const int L = (d & 7) * 128 + (d >> 3);
  const int wq = L & 15;           // w-quad (block covers w = 4wq..4wq+3)
  const int h  = L >> 4;
  const int tx = threadIdx.x;      // lane 0..63
  const int w2 = threadIdx.y;      // 0..3, one wave per w
  const int ln = tx & 31;          // A-row (=batch) and B-col (=o)
  const int half = tx >> 5;        // k-half: holds k = half*8 + e
  const int tid = w2 * 64 + tx;
  const int w = wq * 4 + w2;

  f32x16 acc = {0,0,0,0,0,0,0,0,0,0,0,0,0,0,0,0};

  const int bbase = ln * 36 + w2 * 9;  // LDS dword base (o-row, this wave's w)
  // A base (float index), per-lane row = batch = ln:
  size_t abase;
  if (TRANS) abase = (((size_t)h) * XW_ + w) * 32 + ln;           // + c*139392
  else       abase = (size_t)ln * 69696 + (size_t)h * XW_ + w;    // + c*4356

  for (int s = 0; s < 2; ++s) {
    const int c0 = s * 8;
    __syncthreads();
    // Stage 8 c's of weights: 2304 float4, 9 per thread, coalesced, 16B-aligned.
#pragma unroll
    for (int i = 0; i < 9; ++i) {
      const int f4 = tid + i * 256;
      const int cc = f4 / 288;
      const int rem = f4 - cc * 288;
      const int oo = rem / 9;
      const int q = rem - oo * 9;
      const float4* src = (const float4*)wt +
          (((size_t)oo * CI_ + (c0 + cc)) * H_ + h) * 144 + (size_t)wq * 9 + q;
      ((float4*)wlds)[f4] = *src;
    }
    __syncthreads();

#pragma unroll
    for (int cc = 0; cc < 8; ++cc) {
      const int c = c0 + cc;
      const float* ap = xs + abase + (size_t)c * (TRANS ? 139392 : 4356);

      float av[8] = {0, 0, 0, 0, 0, 0, 0, 0};
      float bv[8] = {0, 0, 0, 0, 0, 0, 0, 0};
      // slot 0: half0 -> kappa0 (i=0,j=0); half1 -> kappa8 (i=2,j=2)
      av[0] = ap[half ? (TRANS ? (2 * XW_ + 2) * 32 : (2 * XW_ + 2)) : 0];
      bv[0] = wlds[cc * 1152 + bbase + (half ? 8 : 0)];
      if (half == 0) {  // slots 1..7: kappa = e -> (i,j) = (e/3, e%3)
#pragma unroll
        for (int e = 1; e < 8; ++e) {
          const int i = e / 3, j = e - 3 * i;
          av[e] = ap[(i * XW_ + j) * (TRANS ? 32 : 1)];
          bv[e] = wlds[cc * 1152 + bbase + e];
        }
      }

      s16x8 af, bf;
#pragma unroll
      for (int e = 0; e < 8; ++e) { af[e] = f2bf(av[e]); bf[e] = f2bf(bv[e]); }
      acc = __builtin_amdgcn_mfma_f32_32x32x16_bf16(af, bf, acc, 0, 0, 0);
    }
  }

  // Epilogue: C/D layout col(o)=lane&31, row(b)=(r&3)+8*(r>>2)+4*half.
  const float bvv = bias[((size_t)ln * H_ + h) * W_ + w];
#pragma unroll
  for (int r = 0; r < 16; ++r) {
    const int b = (r & 3) + 8 * (r >> 2) + 4 * half;
    out[(((size_t)b * 32 + ln) * H_ + h) * W_ + w] = acc[r] + bvv;
  }
}

extern "C" void kernel_launch(void* const* d_in, const int* in_sizes, int n_in,
                              void* d_out, int out_size, void* d_ws, size_t ws_size,
                              hipStream_t stream) {
  const float* x    = (const float*)d_in[0];
  const float* wt   = (const float*)d_in[1];
  const float* bias = (const float*)d_in[2];
  float* out = (float*)d_out;

  dim3 block(64, 4, 1);
  const size_t xt_bytes = (size_t)CI_ * 66 * 66 * 32 * sizeof(float);  // 8.9 MB
  if (ws_size >= xt_bytes) {
    float* xT = (float*)d_ws;
    transpose_x<<<8712, 256, 0, stream>>>(x, xT);
    lc2d_mfma<1><<<1024, block, 0, stream>>>(xT, wt, bias, out);
  } else {
    lc2d_mfma<0><<<1024, block, 0, stream>>>(x, wt, bias, out);
  }
}